// Round 1
// baseline (201.781 us; speedup 1.0000x reference)
//
#include <hip/hip_runtime.h>
#include <float.h>
#include <math.h>

#define DIM   1024
#define NROWS 131072
#define TOPK  32
#define TAU   0.2f

// ---------------------------------------------------------------------------
// Kernel 0: scale = 1 / (max(||q||, 1e-12) * TAU)
// ---------------------------------------------------------------------------
__global__ __launch_bounds__(256) void norm_kernel(const float* __restrict__ q,
                                                   float* __restrict__ scale_out) {
    __shared__ float red[4];
    int t = threadIdx.x;
    float ss = 0.f;
    for (int i = t; i < DIM; i += 256) { float v = q[i]; ss += v * v; }
    #pragma unroll
    for (int off = 32; off > 0; off >>= 1) ss += __shfl_xor(ss, off, 64);
    int wave = t >> 6;
    if ((t & 63) == 0) red[wave] = ss;
    __syncthreads();
    if (t == 0) {
        float s = red[0] + red[1] + red[2] + red[3];
        float nrm = fmaxf(sqrtf(s), 1e-12f);
        scale_out[0] = 1.0f / (nrm * TAU);
    }
}

// ---------------------------------------------------------------------------
// Kernel 1: logits[row] = dot(K[row], query) * scale ; full_attn[row] = 0
// One wave (64 lanes) per row, float4 loads (16B/lane), shfl-xor reduce.
// This kernel streams 512 MB of K -> the HBM-bound hot spot.
// ---------------------------------------------------------------------------
__global__ __launch_bounds__(256) void logits_kernel(const float* __restrict__ Km,
                                                     const float* __restrict__ q,
                                                     const float* __restrict__ scale_p,
                                                     float* __restrict__ logits,
                                                     float* __restrict__ full_attn) {
    const int lane = threadIdx.x & 63;
    const int wave = threadIdx.x >> 6;
    const int gwave = blockIdx.x * 4 + wave;
    const int total_waves = gridDim.x * 4;
    const float scale = scale_p[0];

    // Preload this lane's slice of q: cols lane*4 + c*256 (+0..3), c=0..3
    float4 qv[4];
    #pragma unroll
    for (int c = 0; c < 4; ++c)
        qv[c] = *reinterpret_cast<const float4*>(q + c * 256 + lane * 4);

    for (int row = gwave; row < NROWS; row += total_waves) {
        const float* kr = Km + (size_t)row * DIM;
        float acc = 0.f;
        #pragma unroll
        for (int c = 0; c < 4; ++c) {
            float4 kv = *reinterpret_cast<const float4*>(kr + c * 256 + lane * 4);
            acc += qv[c].x * kv.x + qv[c].y * kv.y + qv[c].z * kv.z + qv[c].w * kv.w;
        }
        #pragma unroll
        for (int off = 32; off > 0; off >>= 1) acc += __shfl_xor(acc, off, 64);
        if (lane == 0) {
            logits[row] = acc * scale;
            full_attn[row] = 0.0f;   // zero; kernel 3 scatters the 32 nonzeros
        }
    }
}

// ---------------------------------------------------------------------------
// Kernel 2: per-block (1 wave) local top-32 of a 512-element chunk.
// 256 blocks -> 8192 (val, idx) candidates. The global top-32 is a subset.
// ---------------------------------------------------------------------------
__global__ __launch_bounds__(64) void topk_local_kernel(const float* __restrict__ logits,
                                                        float* __restrict__ cand_val,
                                                        int* __restrict__ cand_idx) {
    const int lane = threadIdx.x;
    const int base = blockIdx.x * 512;

    float v[8]; int gi[8];
    float4 a = *reinterpret_cast<const float4*>(logits + base + lane * 4);
    float4 b = *reinterpret_cast<const float4*>(logits + base + 256 + lane * 4);
    v[0] = a.x; v[1] = a.y; v[2] = a.z; v[3] = a.w;
    v[4] = b.x; v[5] = b.y; v[6] = b.z; v[7] = b.w;
    #pragma unroll
    for (int j = 0; j < 4; ++j) gi[j] = base + lane * 4 + j;
    #pragma unroll
    for (int j = 0; j < 4; ++j) gi[4 + j] = base + 256 + lane * 4 + j;

    for (int r = 0; r < TOPK; ++r) {
        float m = v[0]; int mi = gi[0];
        #pragma unroll
        for (int j = 1; j < 8; ++j)
            if (v[j] > m || (v[j] == m && gi[j] < mi)) { m = v[j]; mi = gi[j]; }
        #pragma unroll
        for (int off = 32; off > 0; off >>= 1) {
            float ov = __shfl_xor(m, off, 64);
            int   oi = __shfl_xor(mi, off, 64);
            if (ov > m || (ov == m && oi < mi)) { m = ov; mi = oi; }
        }
        #pragma unroll
        for (int j = 0; j < 8; ++j)
            if (gi[j] == mi) v[j] = -FLT_MAX;   // only the owner matches
        if (lane == 0) {
            cand_val[blockIdx.x * TOPK + r] = m;
            cand_idx[blockIdx.x * TOPK + r] = mi;
        }
    }
}

// ---------------------------------------------------------------------------
// Kernel 3 (1 block, 256 threads): global top-32 of 8192 candidates,
// softmax, scatter into full_attn, out = attn @ V[idxs].
// ---------------------------------------------------------------------------
__global__ __launch_bounds__(256) void final_kernel(const float* __restrict__ cand_val,
                                                    const int* __restrict__ cand_idx,
                                                    const float* __restrict__ Vm,
                                                    float* __restrict__ out,
                                                    float* __restrict__ full_attn) {
    const int t = threadIdx.x;
    const int lane = t & 63, wave = t >> 6;
    __shared__ float wred_v[4];
    __shared__ int   wred_i[4];
    __shared__ float tval[TOPK];
    __shared__ int   tidx[TOPK];
    __shared__ float attn_s[TOPK];

    // Each thread holds 32 candidates in registers (static indexing only).
    float v[32]; int gi[32];
    #pragma unroll
    for (int k = 0; k < 32; ++k) {
        int c = t + 256 * k;          // coalesced
        v[k]  = cand_val[c];
        gi[k] = cand_idx[c];
    }

    for (int r = 0; r < TOPK; ++r) {
        float m = v[0]; int mi = gi[0];
        #pragma unroll
        for (int k = 1; k < 32; ++k)
            if (v[k] > m || (v[k] == m && gi[k] < mi)) { m = v[k]; mi = gi[k]; }
        #pragma unroll
        for (int off = 32; off > 0; off >>= 1) {
            float ov = __shfl_xor(m, off, 64);
            int   oi = __shfl_xor(mi, off, 64);
            if (ov > m || (ov == m && oi < mi)) { m = ov; mi = oi; }
        }
        if (lane == 0) { wred_v[wave] = m; wred_i[wave] = mi; }
        __syncthreads();
        m = wred_v[0]; mi = wred_i[0];
        #pragma unroll
        for (int w = 1; w < 4; ++w) {
            float ov = wred_v[w]; int oi = wred_i[w];
            if (ov > m || (ov == m && oi < mi)) { m = ov; mi = oi; }
        }
        #pragma unroll
        for (int k = 0; k < 32; ++k)
            if (gi[k] == mi) v[k] = -FLT_MAX;   // invalidate the winner
        if (t == 0) { tval[r] = m; tidx[r] = mi; }
        __syncthreads();   // protects wred_* reuse AND publishes tval/tidx
    }

    // softmax over the 32 (descending) top values — redundant per thread, cheap
    float mx = tval[0];
    float sum = 0.f;
    #pragma unroll
    for (int j = 0; j < TOPK; ++j) sum += expf(tval[j] - mx);
    if (t < TOPK) attn_s[t] = expf(tval[t] - mx) / sum;
    __syncthreads();

    if (t < TOPK) full_attn[tidx[t]] = attn_s[t];

    // out[d] = sum_j attn[j] * V[idx[j]][d]   (coalesced over d)
    for (int d = t; d < DIM; d += 256) {
        float acc = 0.f;
        #pragma unroll
        for (int j = 0; j < TOPK; ++j)
            acc += attn_s[j] * Vm[(size_t)tidx[j] * DIM + d];
        out[d] = acc;
    }
}

// ---------------------------------------------------------------------------
extern "C" void kernel_launch(void* const* d_in, const int* in_sizes, int n_in,
                              void* d_out, int out_size, void* d_ws, size_t ws_size,
                              hipStream_t stream) {
    const float* q  = (const float*)d_in[0];
    const float* Km = (const float*)d_in[1];
    const float* Vm = (const float*)d_in[2];
    // d_in[3] = topk scalar (32) — fixed by problem setup.

    float* out       = (float*)d_out;       // [0 .. 1024)
    float* full_attn = out + DIM;           // [1024 .. 1024+131072)

    char*  ws       = (char*)d_ws;
    float* scale    = (float*)ws;                       // 1 float
    float* logits   = (float*)(ws + 256);               // NROWS floats
    float* cand_val = logits + NROWS;                   // 8192 floats
    int*   cand_idx = (int*)(cand_val + 8192);          // 8192 ints

    norm_kernel<<<1, 256, 0, stream>>>(q, scale);
    logits_kernel<<<8192, 256, 0, stream>>>(Km, q, scale, logits, full_attn);
    topk_local_kernel<<<NROWS / 512, 64, 0, stream>>>(logits, cand_val, cand_idx);
    final_kernel<<<1, 256, 0, stream>>>(cand_val, cand_idx, Vm, out, full_attn);
}